// Round 1
// baseline (833.542 us; speedup 1.0000x reference)
//
#include <hip/hip_runtime.h>

// Row-wise sparsemax over 4096 x 32000 fp32.
// One block (1024 threads) per row; row lives in registers (8 float4/thread).
// tau found via candidate-set Michelot: support subset of {x > rowmax - 1}.

#define NCOL 32000
#define NV4  8000          // NCOL / 4
#define NT   1024
#define VPT  8             // float4 per thread (1024*8 = 8192 >= 8000)
#define CAP  1024          // candidate list capacity (== NT so init is 1 store/thread)

__global__ __launch_bounds__(NT, 8)
void sparsemax_kernel(const float* __restrict__ x, float* __restrict__ out) {
    __shared__ float sred[16];
    __shared__ float sS[16];
    __shared__ int   sK[16];
    __shared__ float scand[CAP];
    __shared__ int   scnt;

    const int tid  = threadIdx.x;
    const int lane = tid & 63;
    const int wave = tid >> 6;
    const long long row = blockIdx.x;

    const float4* __restrict__ xr   = (const float4*)(x + row * NCOL);
    float4* __restrict__       outr = (float4*)(out + row * NCOL);

    // ---- load row into registers (coalesced float4) ----
    float4 v[VPT];
#pragma unroll
    for (int j = 0; j < VPT; ++j) {
        const int q = tid + j * NT;
        if (j < VPT - 1 || q < NV4) {
            v[j] = xr[q];
        } else {
            v[j] = make_float4(-1e30f, -1e30f, -1e30f, -1e30f);
        }
    }

    // init LDS (before barrier 1)
    scand[tid] = -1e30f;           // CAP == NT
    if (tid == 0) scnt = 0;

    // ---- phase 1: row max ----
    float m = -1e30f;
#pragma unroll
    for (int j = 0; j < VPT; ++j)
        m = fmaxf(m, fmaxf(fmaxf(v[j].x, v[j].y), fmaxf(v[j].z, v[j].w)));
#pragma unroll
    for (int off = 32; off > 0; off >>= 1)
        m = fmaxf(m, __shfl_down(m, off, 64));
    if (lane == 0) sred[wave] = m;
    __syncthreads();
    float M = sred[0];
#pragma unroll
    for (int w = 1; w < 16; ++w) M = fmaxf(M, sred[w]);
    const float thr = M - 1.0f;    // tau* >= M - 1, so support ⊆ {z > thr}

    // ---- phase 2: gather candidates > thr into LDS ----
#pragma unroll
    for (int j = 0; j < VPT; ++j) {
        const float e0 = v[j].x, e1 = v[j].y, e2 = v[j].z, e3 = v[j].w;
        if (e0 > thr) { int p = atomicAdd(&scnt, 1); if (p < CAP) scand[p] = e0; }
        if (e1 > thr) { int p = atomicAdd(&scnt, 1); if (p < CAP) scand[p] = e1; }
        if (e2 > thr) { int p = atomicAdd(&scnt, 1); if (p < CAP) scand[p] = e2; }
        if (e3 > thr) { int p = atomicAdd(&scnt, 1); if (p < CAP) scand[p] = e3; }
    }
    __syncthreads();
    const int cnt = scnt;

    // ---- phase 3: solve for tau (Michelot, exact finite convergence) ----
    float tau;
    if (cnt <= CAP) {
        // every wave solves redundantly from the LDS list (no extra barrier)
        float tau_l = thr;
        int kprev = -1;
        if (cnt <= 64) {
            const float cv = scand[lane];   // padded with -1e30
            for (int it = 0; it < 130; ++it) {
                float Sl = (cv > tau_l) ? cv : 0.0f;
                int   kl = (cv > tau_l) ? 1 : 0;
#pragma unroll
                for (int off = 32; off > 0; off >>= 1) {
                    Sl += __shfl_down(Sl, off, 64);
                    kl += __shfl_down(kl, off, 64);
                }
                const float St = __shfl(Sl, 0, 64);
                const int   kt = __shfl(kl, 0, 64);
                tau_l = (St - 1.0f) / (float)kt;
                if (kt == kprev) break;
                kprev = kt;
            }
        } else {
            const int cr = (cnt + 63) & ~63;   // padded region is -1e30
            for (int it = 0; it < CAP + 2; ++it) {
                float Sl = 0.0f; int kl = 0;
                for (int p = lane; p < cr; p += 64) {
                    const float e = scand[p];
                    if (e > tau_l) { Sl += e; kl++; }
                }
#pragma unroll
                for (int off = 32; off > 0; off >>= 1) {
                    Sl += __shfl_down(Sl, off, 64);
                    kl += __shfl_down(kl, off, 64);
                }
                const float St = __shfl(Sl, 0, 64);
                const int   kt = __shfl(kl, 0, 64);
                tau_l = (St - 1.0f) / (float)kt;
                if (kt == kprev) break;
                kprev = kt;
            }
        }
        tau = tau_l;
    } else {
        // fallback (pathological inputs): full-register Michelot, block reductions
        float tau_l = thr;
        int kprev = -1;
        for (int it = 0; it < 300; ++it) {
            float Sl = 0.0f; int kl = 0;
#pragma unroll
            for (int j = 0; j < VPT; ++j) {
                const float e0 = v[j].x, e1 = v[j].y, e2 = v[j].z, e3 = v[j].w;
                if (e0 > tau_l) { Sl += e0; kl++; }
                if (e1 > tau_l) { Sl += e1; kl++; }
                if (e2 > tau_l) { Sl += e2; kl++; }
                if (e3 > tau_l) { Sl += e3; kl++; }
            }
#pragma unroll
            for (int off = 32; off > 0; off >>= 1) {
                Sl += __shfl_down(Sl, off, 64);
                kl += __shfl_down(kl, off, 64);
            }
            if (lane == 0) { sS[wave] = Sl; sK[wave] = kl; }
            __syncthreads();
            float St = 0.0f; int kt = 0;
#pragma unroll
            for (int w = 0; w < 16; ++w) { St += sS[w]; kt += sK[w]; }
            const float tnew = (St - 1.0f) / (float)kt;
            __syncthreads();               // protect sS/sK reuse next iter
            tau_l = tnew;
            if (kt == kprev) break;
            kprev = kt;
        }
        tau = tau_l;
    }

    // ---- phase 4: write output ----
#pragma unroll
    for (int j = 0; j < VPT; ++j) {
        const int q = tid + j * NT;
        if (j < VPT - 1 || q < NV4) {
            float4 o;
            o.x = fmaxf(v[j].x - tau, 0.0f);
            o.y = fmaxf(v[j].y - tau, 0.0f);
            o.z = fmaxf(v[j].z - tau, 0.0f);
            o.w = fmaxf(v[j].w - tau, 0.0f);
            outr[q] = o;
        }
    }
}

extern "C" void kernel_launch(void* const* d_in, const int* in_sizes, int n_in,
                              void* d_out, int out_size, void* d_ws, size_t ws_size,
                              hipStream_t stream) {
    const float* x = (const float*)d_in[0];
    float* out = (float*)d_out;
    const int rows = in_sizes[0] / NCOL;   // 4096
    sparsemax_kernel<<<rows, NT, 0, stream>>>(x, out);
}